// Round 11
// baseline (145.336 us; speedup 1.0000x reference)
//
#include <hip/hip_runtime.h>
#include <hip/hip_fp16.h>

// Problem constants (from reference setup_inputs)
#define B 4
#define C 3
#define H 1024
#define W 1024
#define N (H * W)
#define EPS 1e-8f

// Counting-sort bin-and-gather splat: each block owns a 32x32 output tile.
// Sources from the tile+8px window are BIN-SORTED in LDS by integer cell
// (x0,y0) via count -> packed prefix scan -> place. Each output cell gathers
// its neighboring bins as CONTIGUOUS record ranges, accumulating den + 3
// channels in fp32 registers (no fp atomics; r2: ds_add_f32 bulk scatter is
// ~1 lane-op/cy).
//
// r9 POST-MORTEM (absmax 3.53 FAIL): half2 fractions (dw 4.9e-4) blew up at
// low-denominator cells -- absmax error ~ dv*dw/den, and den ~ 1e-3 cells
// are common at 4M outputs. WEIGHT precision (not value precision) drives
// absmax. Fractions MUST stay u16 fixed-point (dw 1.5e-5, r8-proven).
//
// vs r8 (54 us splat / 145 total; VALU-issue-bound):
//  RANK-CARRY kept from r9: A1's counting atomicAdd RETURN is this source's
//  within-bin rank, carried in packed u8x4 regs. A2 places at
//  start[bin]+rank via a plain LDS read -- NO atomic-with-return chain, and
//  binCntP keeps PRISTINE exclusive starts through Phase B:
//  (e0,m,e1) = start[bin0..bin0+2], bin0==0 special case gone.
//  rank>=255 or slot>=NREC -> exact spill.
// Carried: register-carry A1->A2 (no grid reload), NREC=1536 cap with exact
// spill, outlier pre-filter |disp|<=6, im0-load skip for empty tasks,
// nontemporal out/den stores, 17 920 B LDS -> 8 blocks/CU.
#define TW 32
#define TH 32
#define R 8
#define WIN 48                 // TW + 2R
#define NSRC (WIN * WIN)       // 2304 window sources
#define NTASKS (NSRC / 4)      // 576 float4-groups
#define COLG (WIN / 4)         // 12
#define BDIM 33                // bins per axis: x0 in [tx0-1, tx0+31]
#define NBINS (BDIM * BDIM)    // 1089
#define NBINW ((NBINS + 1) / 2)// 545 packed words (slots 0..1089 incl. total)
#define NREC 1536              // record capacity (cap, exact spill path)
#define NTX (W / TW)           // 32
#define NTY (H / TH)           // 32
#define NTILES (NTX * NTY * B) // 4096

struct OutlierRec { int idx; float dw, d0, d1, d2; };  // idx = b*N + cell

__global__ __launch_bounds__(256, 8) void splat_gather(
    const float* __restrict__ im0,   // [B,C,H,W]
    const float* __restrict__ grid,  // [B,H,W,2]
    float* __restrict__ out,         // [B,C,H,W] NORMALIZED output
    float* __restrict__ den,         // [B,N] denominators (for fixup)
    int* __restrict__ tileCnt,       // [NTILES] record counts (pre-zeroed)
    OutlierRec* __restrict__ recs,   // [NTILES*slots]
    int slots)
{
    __shared__ uint2 rec01[NREC];           // 12288 B (x: dy<<16|dx u16 fx, y: half2(v0,v1))
    __shared__ unsigned short recV2[NREC];  //  3072 B (half(v2) bits)
    __shared__ unsigned binCntP[NBINW];     //  2180 B (2 x u16 per word)
    __shared__ int wtot[4];                 // wave totals for the scan
    // total 17 556 B -> 17 920 alloc -> 8 blocks/CU

    const int bid = blockIdx.x;
    const int b = bid >> 10;             // 1024 tiles per image
    const int t = bid & 1023;
    const int tx0 = (t & (NTX - 1)) * TW;
    const int ty0 = (t >> 5) * TH;
    const int tid = threadIdx.x;

    for (int i = tid; i < NBINW; i += 256) binCntP[i] = 0u;
    __syncthreads();

    const int lx0 = tx0 - R;
    const int ly0 = ty0 - R;

    const float* imb   = im0 + (size_t)b * C * N;
    const float* gbase = grid + (size_t)b * N * 2;

    // helper: push an exact fp32 record to a tile's fixup list
    auto push_rec = [&](int xi, int yi, float w, float v0, float v1, float v2) {
        const int tile = (b << 10) | ((yi >> 5) << 5) | (xi >> 5);
        const int slot = atomicAdd(&tileCnt[tile], 1);
        if (slot < slots) {
            OutlierRec r;
            r.idx = b * N + yi * W + xi;
            r.dw = w; r.d0 = v0 * w; r.d1 = v1 * w; r.d2 = v2 * w;
            recs[(size_t)tile * slots + slot] = r;
        }
    };

    // Per-source register cache carried A1 -> A2 (all indices compile-time).
    unsigned cw[3][4];     // packed fractions dq | eq<<16 (u16 fixed-point)
    unsigned cbp[3][2];    // 2 x u16 per word: (bin+1) | outlier<<15
    unsigned cr[3];        // 4 x u8 within-bin rank (255 = spill marker)

    // ---- Phase A1: count sources per bin (grid loads only) ----
#pragma unroll
    for (int it = 0; it < 3; ++it) {
        cbp[it][0] = 0u; cbp[it][1] = 0u; cr[it] = 0u;
        if (it == 2 && tid >= NTASKS - 512) continue;   // only tid<64 has task 3
        const int task = tid + it * 256;
        const int row = task / COLG;                    // 0..47
        const int col = (task - row * COLG) * 4;        // 0,4,...,44
        const int sy = ly0 + row;
        const int sxg = lx0 + col;
        if ((unsigned)sy >= H || (unsigned)sxg >= W) continue;

        const int n = sy * W + sxg;
        const float4 g0 = *(const float4*)(gbase + 2 * n);
        const float4 g1 = *(const float4*)(gbase + 2 * n + 4);
        const float gxk[4] = {g0.x, g0.z, g1.x, g1.z};
        const float gyk[4] = {g0.y, g0.w, g1.y, g1.w};

        unsigned cv[4];
        unsigned rk[4];
#pragma unroll
        for (int k = 0; k < 4; ++k) {
            const int sx = sxg + k;
            const float gx = gxk[k], gy = gyk[k];
            const float x0f = floorf(gx);
            const float y0f = floorf(gy);
            const float dx = gx - x0f;
            const float dy = gy - y0f;
            const int x0 = (int)x0f;
            const int y0 = (int)y0f;

            {
                unsigned dq = (unsigned)(dx * 65536.0f);
                unsigned eq = (unsigned)(dy * 65536.0f);
                if (dq > 65535u) dq = 65535u;
                if (eq > 65535u) eq = 65535u;
                cw[it][k] = dq | (eq << 16);
            }

            unsigned c = 0u;
            unsigned r = 0u;
            const int bx = x0 - tx0 + 1;
            const int by = y0 - ty0 + 1;
            if ((unsigned)bx < BDIM && (unsigned)by < BDIM) {
                const int bin = by * BDIM + bx;
                const unsigned sh = (unsigned)(bin & 1) * 16u;
                const unsigned old = atomicAdd(&binCntP[bin >> 1], 1u << sh);
                r = (old >> sh) & 0xffffu;      // within-bin rank
                if (r > 255u) r = 255u;         // spill marker
                c = (unsigned)(bin + 1);
            }
            // owner-outlier pre-filter: |disp|<=6 on both axes guarantees all
            // corners covered by their owners' windows.
            if ((unsigned)(sx - tx0) < TW && (unsigned)(sy - ty0) < TH) {
                if (!(fabsf(gx - (float)sx) <= 6.f &&
                      fabsf(gy - (float)sy) <= 6.f)) {
                    bool outl = false;
#pragma unroll
                    for (int cy2 = 0; cy2 < 2; ++cy2)
#pragma unroll
                        for (int cx2 = 0; cx2 < 2; ++cx2) {
                            const int xi = x0 + cx2, yi = y0 + cy2;
                            if ((unsigned)xi < W && (unsigned)yi < H) {
                                const int ox0 = (xi >> 5) << 5;
                                const int oy0 = (yi >> 5) << 5;
                                if (sx < ox0 - R || sx >= ox0 + TW + R ||
                                    sy < oy0 - R || sy >= oy0 + TH + R)
                                    outl = true;
                            }
                        }
                    if (outl) c |= 0x8000u;
                }
            }
            cv[k] = c;
            rk[k] = r;
        }
        cbp[it][0] = cv[0] | (cv[1] << 16);
        cbp[it][1] = cv[2] | (cv[3] << 16);
        cr[it] = rk[0] | (rk[1] << 8) | (rk[2] << 16) | (rk[3] << 24);
    }
    __syncthreads();

    // ---- Scan: exclusive prefix over bins 0..1089, in place, packed u16 ----
    // Thread owns 6 consecutive slots = 3 whole packed words. Slot 1089
    // (count 0) receives start[1089] = total binned, used by Phase B's e1
    // at the last bin row.
    {
        int c[6] = {0, 0, 0, 0, 0, 0};
        const int w0 = tid * 3;
        const bool act = (tid * 6) < NBINS;
        if (act) {
#pragma unroll
            for (int j = 0; j < 3; ++j) {
                const int w = w0 + j;
                const unsigned wv = (w < NBINW) ? binCntP[w] : 0u;
                c[2 * j]     = (int)(wv & 0xffffu);
                c[2 * j + 1] = (int)(wv >> 16);
            }
        }
        const int tsum = c[0] + c[1] + c[2] + c[3] + c[4] + c[5];
        int x = tsum;
#pragma unroll
        for (int off = 1; off < 64; off <<= 1) {
            const int y = __shfl_up(x, off);
            if ((tid & 63) >= off) x += y;
        }
        if ((tid & 63) == 63) wtot[tid >> 6] = x;
        __syncthreads();
        int ex = x - tsum;                         // exclusive within wave
        for (int i = 0; i < (tid >> 6); ++i) ex += wtot[i];
        if (act) {
#pragma unroll
            for (int j = 0; j < 3; ++j) {
                const int w = w0 + j;
                if (w < NBINW) {
                    const unsigned lo = (unsigned)ex; ex += c[2 * j];
                    const unsigned hi = (unsigned)ex; ex += c[2 * j + 1];
                    binCntP[w] = (lo & 0xffffu) | (hi << 16);
                }
            }
        }
    }
    __syncthreads();

    // ---- Phase A2: place records at start[bin]+rank (NO atomics, NO grid
    //      reload; im0 loads only for non-empty tasks) ----
#pragma unroll
    for (int it = 0; it < 3; ++it) {
        if (it == 2 && tid >= NTASKS - 512) continue;
        const unsigned p0 = cbp[it][0], p1 = cbp[it][1];
        if (!(p0 | p1)) continue;       // nothing binned, no outliers
        const int task = tid + it * 256;
        const int row = task / COLG;
        const int col = (task - row * COLG) * 4;
        const int sy = ly0 + row;
        const int sxg = lx0 + col;
        const int n = sy * W + sxg;
        const float4 c0 = *(const float4*)(imb + n);
        const float4 c1 = *(const float4*)(imb + N + n);
        const float4 c2 = *(const float4*)(imb + 2 * N + n);
        const float v0k[4] = {c0.x, c0.y, c0.z, c0.w};
        const float v1k[4] = {c1.x, c1.y, c1.z, c1.w};
        const float v2k[4] = {c2.x, c2.y, c2.z, c2.w};

#pragma unroll
        for (int k = 0; k < 4; ++k) {
            const unsigned cv = (((k & 2) ? p1 : p0) >> ((k & 1) * 16)) & 0xffffu;
            const unsigned binp1 = cv & 0x7fffu;
            if (binp1) {
                const int bin = (int)binp1 - 1;
                const int rank = (int)((cr[it] >> (k * 8)) & 0xffu);
                const unsigned sw = binCntP[bin >> 1];
                const int start = (int)((sw >> ((unsigned)(bin & 1) * 16u)) & 0xffffu);
                const int slot = start + rank;
                if (rank < 255 && slot < NREC) {
                    __half2 h01 = __floats2half2_rn(v0k[k], v1k[k]);
                    uint2 r; r.x = cw[it][k]; r.y = *(unsigned*)&h01;
                    rec01[slot] = r;
                    recV2[slot] = __half_as_ushort(__float2half_rn(v2k[k]));
                } else {
                    // capacity spill (rare): exact records for corners in MY
                    // tile (neighbor tiles handle theirs).
                    const unsigned w0 = cw[it][k];
                    const float dx = (float)(w0 & 0xffffu) * (1.f / 65536.f);
                    const float dy = (float)(w0 >> 16) * (1.f / 65536.f);
                    const int x0 = tx0 - 1 + bin % BDIM;
                    const int y0 = ty0 - 1 + bin / BDIM;
                    const float wxa[2] = {1.f - dx, dx};
                    const float wya[2] = {1.f - dy, dy};
#pragma unroll
                    for (int cy2 = 0; cy2 < 2; ++cy2)
#pragma unroll
                        for (int cx2 = 0; cx2 < 2; ++cx2) {
                            const int xi = x0 + cx2, yi = y0 + cy2;
                            if ((unsigned)(xi - tx0) < TW &&
                                (unsigned)(yi - ty0) < TH)
                                push_rec(xi, yi, wxa[cx2] * wya[cy2],
                                         v0k[k], v1k[k], v2k[k]);
                        }
                }
            }
            if (cv & 0x8000u) {
                // rare flagged outlier: reload this source's grid scalar
                const int sx = sxg + k;
                const float gx = gbase[2 * (n + k)];
                const float gy = gbase[2 * (n + k) + 1];
                const float x0f = floorf(gx);
                const float y0f = floorf(gy);
                const float dx = gx - x0f;
                const float dy = gy - y0f;
                const int x0 = (int)x0f;
                const int y0 = (int)y0f;
                const float wxa[2] = {1.f - dx, dx};
                const float wya[2] = {1.f - dy, dy};
#pragma unroll
                for (int cy2 = 0; cy2 < 2; ++cy2)
#pragma unroll
                    for (int cx2 = 0; cx2 < 2; ++cx2) {
                        const int xi = x0 + cx2, yi = y0 + cy2;
                        if ((unsigned)xi < W && (unsigned)yi < H) {
                            const int ox0 = (xi >> 5) << 5;
                            const int oy0 = (yi >> 5) << 5;
                            const bool covered =
                                (sx >= ox0 - R) && (sx < ox0 + TW + R) &&
                                (sy >= oy0 - R) && (sy < oy0 + TH + R);
                            if (!covered)
                                push_rec(xi, yi, wxa[cx2] * wya[cy2],
                                         v0k[k], v1k[k], v2k[k]);
                        }
                    }
            }
        }
    }
    __syncthreads();

    // ---- Phase B: gather contiguous bin ranges, row-merged ----
    // binCntP holds PRISTINE exclusive starts: (e0,m,e1) = start[bin0],
    // start[bin0+1], start[bin0+2] -- 3 u16s spanning exactly 2 consecutive
    // words. Thread owns 4 consecutive output rows; bin row by = ry+s feeds
    // cell row by-1 (wy=1-dy) and by (wy=dy). Range [e0,e1) boundary m:
    // e<m -> x0==cx-1 -> wx=dx, e>=m -> wx=1-dx. Clamp to NREC (spills are
    // exact via fix_tiles).
    const int cx = tid & 31;
    const int ry = (tid >> 5) * 4;
    float* outb = out + (size_t)b * C * N;
    float* denb = den + (size_t)b * N;

    float d[4]  = {0.f, 0.f, 0.f, 0.f};
    float a0[4] = {0.f, 0.f, 0.f, 0.f};
    float a1[4] = {0.f, 0.f, 0.f, 0.f};
    float a2[4] = {0.f, 0.f, 0.f, 0.f};

#pragma unroll
    for (int s = 0; s < 5; ++s) {        // bin row by = ry + s
        const int by = ry + s;
        const int bin0 = by * BDIM + cx;
        const int w = bin0 >> 1;
        const unsigned wa = binCntP[w];
        const unsigned wb = binCntP[w + 1];
        int e0, m, e1;
        if (bin0 & 1) {                  // wa={.., start[bin0]}, wb={start[+1], start[+2]}
            e0 = (int)(wa >> 16); m = (int)(wb & 0xffffu);
            e1 = (int)(wb >> 16);
        } else {                         // wa={start[bin0], start[+1]}, wb={start[+2], ..}
            e0 = (int)(wa & 0xffffu); m = (int)(wa >> 16);
            e1 = (int)(wb & 0xffffu);
        }
        e0 = min(e0, NREC); m = min(m, NREC); e1 = min(e1, NREC);
        for (int e = e0; e < e1; ++e) {
            const uint2 rw = rec01[e];
            const float dx = (float)(rw.x & 0xffffu) * (1.f / 65536.f);
            const float dy = (float)(rw.x >> 16) * (1.f / 65536.f);
            const float2 v01 = __half22float2(*(const __half2*)&rw.y);
            const float v2 = __half2float(__ushort_as_half(recV2[e]));
            const float wx = (e < m) ? dx : (1.f - dx);
            if (s > 0) {                 // cell row by-1: wy = 1-dy
                const float w2 = wx * (1.f - dy);
                d[s - 1] += w2;
                a0[s - 1] += v01.x * w2;
                a1[s - 1] += v01.y * w2;
                a2[s - 1] += v2 * w2;
            }
            if (s < 4) {                 // cell row by: wy = dy
                const float w2 = wx * dy;
                d[s] += w2;
                a0[s] += v01.x * w2;
                a1[s] += v01.y * w2;
                a2[s] += v2 * w2;
            }
        }
    }

#pragma unroll
    for (int s = 0; s < 4; ++s) {
        const float inv = 1.f / fmaxf(d[s], EPS);
        const int gi = (ty0 + ry + s) * W + tx0 + cx;
        __builtin_nontemporal_store(d[s], denb + gi);
        __builtin_nontemporal_store(a0[s] * inv, outb + gi);
        __builtin_nontemporal_store(a1[s] * inv, outb + N + gi);
        __builtin_nontemporal_store(a2[s] * inv, outb + 2 * N + gi);
    }
}

// Apply fixup records exactly: un-normalize affected cells, add, re-normalize.
// One block per tile; records for the same cell are merged (first-index wins).
__global__ __launch_bounds__(64) void fix_tiles(
    float* __restrict__ out,          // [B,C,N] normalized
    float* __restrict__ den,          // [B,N]
    const int* __restrict__ tileCnt,
    const OutlierRec* __restrict__ recs,
    int slots)
{
    const int bid = blockIdx.x;
    int cnt = tileCnt[bid];
    if (cnt <= 0) return;
    cnt = min(cnt, slots);
    const int tid = threadIdx.x;
    if (tid >= cnt) return;

    OutlierRec rec = recs[(size_t)bid * slots + tid];
    float dw = rec.dw, d0 = rec.d0, d1 = rec.d1, d2 = rec.d2;
    bool first = true;
    for (int r2 = 0; r2 < cnt; ++r2) {
        if (r2 == tid) continue;
        OutlierRec o = recs[(size_t)bid * slots + r2];
        if (o.idx == rec.idx) {
            if (r2 < tid) { first = false; break; }
            dw += o.dw; d0 += o.d0; d1 += o.d1; d2 += o.d2;
        }
    }
    if (!first) return;

    const int b = rec.idx >> 20;          // idx / N
    const int cell = rec.idx & (N - 1);
    float* outb = out + (size_t)b * C * N + cell;
    float* dptr = den + ((size_t)b << 20) + cell;

    float d = *dptr;
    const float m = fmaxf(d, EPS);
    float n0 = outb[0] * m;               // recover numerators
    float n1 = outb[N] * m;
    float n2 = outb[2 * N] * m;
    d += dw; n0 += d0; n1 += d1; n2 += d2;
    const float inv = 1.f / fmaxf(d, EPS);
    *dptr = d;
    outb[0]     = n0 * inv;
    outb[N]     = n1 * inv;
    outb[2 * N] = n2 * inv;
}

extern "C" void kernel_launch(void* const* d_in, const int* in_sizes, int n_in,
                              void* d_out, int out_size, void* d_ws, size_t ws_size,
                              hipStream_t stream) {
    const float* im0 = (const float*)d_in[0];   // [B,C,H,W] fp32
    const float* grid = (const float*)d_in[1];  // [B,H,W,2] fp32
    float* out = (float*)d_out;                 // [B,C,H,W] fp32

    // ws layout: [0,16K): per-tile record counts | [16K, 16K+16MB): den |
    //            rest: per-tile fixup record slots
    int* tileCnt = (int*)d_ws;
    float* den = (float*)((char*)d_ws + 16384);
    const size_t rec_off = 16384 + (size_t)B * N * sizeof(float);
    OutlierRec* recs = (OutlierRec*)((char*)d_ws + rec_off);
    int slots = 0;
    if (ws_size > rec_off) {
        size_t avail = (ws_size - rec_off) / sizeof(OutlierRec);
        slots = (int)(avail / NTILES);
        if (slots > 32) slots = 32;
    }

    (void)hipMemsetAsync(tileCnt, 0, NTILES * sizeof(int), stream);

    splat_gather<<<NTILES, 256, 0, stream>>>(im0, grid, out, den,
                                             tileCnt, recs, slots);
    fix_tiles<<<NTILES, 64, 0, stream>>>(out, den, tileCnt, recs, slots);
}

// Round 12
// 145.248 us; speedup vs baseline: 1.0006x; 1.0006x over previous
//
#include <hip/hip_runtime.h>
#include <hip/hip_fp16.h>

// Problem constants (from reference setup_inputs)
#define B 4
#define C 3
#define H 1024
#define W 1024
#define N (H * W)
#define EPS 1e-8f

// Counting-sort bin-and-gather splat: each block owns a 32x32 output tile.
// Sources from the tile+8px window are BIN-SORTED in LDS by integer cell
// (x0,y0) via count -> packed prefix scan -> place (cursor atomics). Each
// output cell gathers its neighboring bins as CONTIGUOUS record ranges,
// accumulating den + 3 channels in fp32 registers (no fp atomics; r2:
// ds_add_f32 bulk scatter is ~1 lane-op/cy).
//
// r11 POST-MORTEM: rank-carry REGRESSED splat 54->60.5 us. A1's counting
// atomic with UNUSED return compiles to no-return ds_add_u32 (cheap); using
// the return (rank) forces ds_add_rtn_b32 -> ~120cy dependent wait per
// source in A1 (9/thread) > the A2 atomic chain it removed (4.5/thread).
// REVERTED to r8's structure (no-return A1 atomic, A2 cursor atomics).
// r9 POST-MORTEM: fractions MUST stay u16 fixed-point (dw 1.5e-5) -- weight
// precision drives absmax through low-denominator cells (half2 -> 3.53 FAIL).
//
// vs r8 (54 us splat / 145 total; VALU-issue-bound, VALU 64%):
//  (1) LATE PACK: only ~50% of window sources bin; dq/eq pack (6 ops) moved
//      inside the bin-hit branch (cw only read by A2 when binned).
//  (2) PACKED FP32 Phase B: accumulate float2 (den,a0) + (a1,a2) -> two
//      v_pk_fma_f32 per record-row (was 1 mul + 4 fma); weight pair via
//      wx*(1-dy) = wx - wx*dy (1 mul + 1 sub for both rows).
// Carried: register-carry A1->A2 (no grid reload), NREC=1536 cap with exact
// spill, outlier pre-filter |disp|<=6, im0-load skip for empty tasks,
// nontemporal out/den stores, 17 920 B LDS -> 8 blocks/CU.
#define TW 32
#define TH 32
#define R 8
#define WIN 48                 // TW + 2R
#define NSRC (WIN * WIN)       // 2304 window sources
#define NTASKS (NSRC / 4)      // 576 float4-groups
#define COLG (WIN / 4)         // 12
#define BDIM 33                // bins per axis: x0 in [tx0-1, tx0+31]
#define NBINS (BDIM * BDIM)    // 1089
#define NBINW ((NBINS + 1) / 2)// 545 packed words (2 x u16 each)
#define NREC 1536              // record capacity (cap, exact spill path)
#define NTX (W / TW)           // 32
#define NTY (H / TH)           // 32
#define NTILES (NTX * NTY * B) // 4096

struct OutlierRec { int idx; float dw, d0, d1, d2; };  // idx = b*N + cell

__global__ __launch_bounds__(256, 8) void splat_gather(
    const float* __restrict__ im0,   // [B,C,H,W]
    const float* __restrict__ grid,  // [B,H,W,2]
    float* __restrict__ out,         // [B,C,H,W] NORMALIZED output
    float* __restrict__ den,         // [B,N] denominators (for fixup)
    int* __restrict__ tileCnt,       // [NTILES] record counts (pre-zeroed)
    OutlierRec* __restrict__ recs,   // [NTILES*slots]
    int slots)
{
    __shared__ uint2 rec01[NREC];           // 12288 B (x: dy<<16|dx u16 fx, y: half2(v0,v1))
    __shared__ unsigned short recV2[NREC];  //  3072 B (half(v2) bits)
    __shared__ unsigned binCntP[NBINW];     //  2180 B (2 x u16 per word)
    __shared__ int wtot[4];                 // wave totals for the scan
    // total 17 556 B -> 17 920 alloc -> 8 blocks/CU

    const int bid = blockIdx.x;
    const int b = bid >> 10;             // 1024 tiles per image
    const int t = bid & 1023;
    const int tx0 = (t & (NTX - 1)) * TW;
    const int ty0 = (t >> 5) * TH;
    const int tid = threadIdx.x;

    for (int i = tid; i < NBINW; i += 256) binCntP[i] = 0u;
    __syncthreads();

    const int lx0 = tx0 - R;
    const int ly0 = ty0 - R;

    const float* imb   = im0 + (size_t)b * C * N;
    const float* gbase = grid + (size_t)b * N * 2;

    // helper: push an exact fp32 record to a tile's fixup list
    auto push_rec = [&](int xi, int yi, float w, float v0, float v1, float v2) {
        const int tile = (b << 10) | ((yi >> 5) << 5) | (xi >> 5);
        const int slot = atomicAdd(&tileCnt[tile], 1);
        if (slot < slots) {
            OutlierRec r;
            r.idx = b * N + yi * W + xi;
            r.dw = w; r.d0 = v0 * w; r.d1 = v1 * w; r.d2 = v2 * w;
            recs[(size_t)tile * slots + slot] = r;
        }
    };

    // Per-source register cache carried A1 -> A2 (all indices compile-time).
    unsigned cw[3][4];     // packed fractions dq | eq<<16 (valid iff binned)
    unsigned cbp[3][2];    // 2 x u16 per word: (bin+1) | outlier<<15

    // ---- Phase A1: count sources per bin (grid loads only; no-return
    //      atomic -> cheap ds_add_u32) ----
#pragma unroll
    for (int it = 0; it < 3; ++it) {
        cbp[it][0] = 0u; cbp[it][1] = 0u;
        if (it == 2 && tid >= NTASKS - 512) continue;   // only tid<64 has task 3
        const int task = tid + it * 256;
        const int row = task / COLG;                    // 0..47
        const int col = (task - row * COLG) * 4;        // 0,4,...,44
        const int sy = ly0 + row;
        const int sxg = lx0 + col;
        if ((unsigned)sy >= H || (unsigned)sxg >= W) continue;

        const int n = sy * W + sxg;
        const float4 g0 = *(const float4*)(gbase + 2 * n);
        const float4 g1 = *(const float4*)(gbase + 2 * n + 4);
        const float gxk[4] = {g0.x, g0.z, g1.x, g1.z};
        const float gyk[4] = {g0.y, g0.w, g1.y, g1.w};

        unsigned cv[4];
#pragma unroll
        for (int k = 0; k < 4; ++k) {
            const int sx = sxg + k;
            const float gx = gxk[k], gy = gyk[k];
            const float x0f = floorf(gx);
            const float y0f = floorf(gy);
            const float dx = gx - x0f;
            const float dy = gy - y0f;
            const int x0 = (int)x0f;
            const int y0 = (int)y0f;

            unsigned c = 0u;
            const int bx = x0 - tx0 + 1;
            const int by = y0 - ty0 + 1;
            if ((unsigned)bx < BDIM && (unsigned)by < BDIM) {
                const int bin = by * BDIM + bx;
                atomicAdd(&binCntP[bin >> 1],
                          1u << ((unsigned)(bin & 1) * 16u));
                c = (unsigned)(bin + 1);
                // LATE PACK: fractions only needed for binned sources.
                unsigned dq = (unsigned)(dx * 65536.0f);
                unsigned eq = (unsigned)(dy * 65536.0f);
                if (dq > 65535u) dq = 65535u;
                if (eq > 65535u) eq = 65535u;
                cw[it][k] = dq | (eq << 16);
            }
            // owner-outlier pre-filter: |disp|<=6 on both axes guarantees all
            // corners covered by their owners' windows.
            if ((unsigned)(sx - tx0) < TW && (unsigned)(sy - ty0) < TH) {
                if (!(fabsf(gx - (float)sx) <= 6.f &&
                      fabsf(gy - (float)sy) <= 6.f)) {
                    bool outl = false;
#pragma unroll
                    for (int cy2 = 0; cy2 < 2; ++cy2)
#pragma unroll
                        for (int cx2 = 0; cx2 < 2; ++cx2) {
                            const int xi = x0 + cx2, yi = y0 + cy2;
                            if ((unsigned)xi < W && (unsigned)yi < H) {
                                const int ox0 = (xi >> 5) << 5;
                                const int oy0 = (yi >> 5) << 5;
                                if (sx < ox0 - R || sx >= ox0 + TW + R ||
                                    sy < oy0 - R || sy >= oy0 + TH + R)
                                    outl = true;
                            }
                        }
                    if (outl) c |= 0x8000u;
                }
            }
            cv[k] = c;
        }
        cbp[it][0] = cv[0] | (cv[1] << 16);
        cbp[it][1] = cv[2] | (cv[3] << 16);
    }
    __syncthreads();

    // ---- Scan: exclusive prefix over 1089 bins, in place, packed u16 ----
    // Thread owns 6 consecutive bins = 3 whole packed words.
    {
        int c[6] = {0, 0, 0, 0, 0, 0};
        const int w0 = tid * 3;
        const bool act = (tid * 6) < NBINS;
        if (act) {
#pragma unroll
            for (int j = 0; j < 3; ++j) {
                const int w = w0 + j;
                const unsigned wv = (w < NBINW) ? binCntP[w] : 0u;
                c[2 * j]     = (int)(wv & 0xffffu);
                c[2 * j + 1] = (int)(wv >> 16);
            }
        }
        const int tsum = c[0] + c[1] + c[2] + c[3] + c[4] + c[5];
        int x = tsum;
#pragma unroll
        for (int off = 1; off < 64; off <<= 1) {
            const int y = __shfl_up(x, off);
            if ((tid & 63) >= off) x += y;
        }
        if ((tid & 63) == 63) wtot[tid >> 6] = x;
        __syncthreads();
        int ex = x - tsum;                         // exclusive within wave
        for (int i = 0; i < (tid >> 6); ++i) ex += wtot[i];
        if (act) {
#pragma unroll
            for (int j = 0; j < 3; ++j) {
                const int w = w0 + j;
                if (w < NBINW) {
                    const unsigned lo = (unsigned)ex; ex += c[2 * j];
                    const unsigned hi = (unsigned)ex; ex += c[2 * j + 1];
                    binCntP[w] = (lo & 0xffffu) | (hi << 16);
                }
            }
        }
    }
    __syncthreads();

    // ---- Phase A2: place records bin-sorted via cursor atomics (im0 loads;
    //      NO grid reload) ----
#pragma unroll
    for (int it = 0; it < 3; ++it) {
        if (it == 2 && tid >= NTASKS - 512) continue;
        const unsigned p0 = cbp[it][0], p1 = cbp[it][1];
        if (!(p0 | p1)) continue;       // nothing binned, no outliers
        const int task = tid + it * 256;
        const int row = task / COLG;
        const int col = (task - row * COLG) * 4;
        const int sy = ly0 + row;
        const int sxg = lx0 + col;
        const int n = sy * W + sxg;
        const float4 c0 = *(const float4*)(imb + n);
        const float4 c1 = *(const float4*)(imb + N + n);
        const float4 c2 = *(const float4*)(imb + 2 * N + n);
        const float v0k[4] = {c0.x, c0.y, c0.z, c0.w};
        const float v1k[4] = {c1.x, c1.y, c1.z, c1.w};
        const float v2k[4] = {c2.x, c2.y, c2.z, c2.w};

#pragma unroll
        for (int k = 0; k < 4; ++k) {
            const unsigned cv = (((k & 2) ? p1 : p0) >> ((k & 1) * 16)) & 0xffffu;
            const unsigned binp1 = cv & 0x7fffu;
            if (binp1) {
                const int bin = (int)binp1 - 1;
                const unsigned sh = (unsigned)(bin & 1) * 16u;
                const unsigned old = atomicAdd(&binCntP[bin >> 1], 1u << sh);
                const int slot = (int)((old >> sh) & 0xffffu);
                const unsigned w0 = cw[it][k];
                if (slot < NREC) {
                    __half2 h01 = __floats2half2_rn(v0k[k], v1k[k]);
                    uint2 r; r.x = w0; r.y = *(unsigned*)&h01;
                    rec01[slot] = r;
                    recV2[slot] = __half_as_ushort(__float2half_rn(v2k[k]));
                } else {
                    // capacity spill (rare): exact records for corners in MY
                    // tile (neighbor tiles handle theirs).
                    const float dx = (float)(w0 & 0xffffu) * (1.f / 65536.f);
                    const float dy = (float)(w0 >> 16) * (1.f / 65536.f);
                    const int x0 = tx0 - 1 + bin % BDIM;
                    const int y0 = ty0 - 1 + bin / BDIM;
                    const float wxa[2] = {1.f - dx, dx};
                    const float wya[2] = {1.f - dy, dy};
#pragma unroll
                    for (int cy2 = 0; cy2 < 2; ++cy2)
#pragma unroll
                        for (int cx2 = 0; cx2 < 2; ++cx2) {
                            const int xi = x0 + cx2, yi = y0 + cy2;
                            if ((unsigned)(xi - tx0) < TW &&
                                (unsigned)(yi - ty0) < TH)
                                push_rec(xi, yi, wxa[cx2] * wya[cy2],
                                         v0k[k], v1k[k], v2k[k]);
                        }
                }
            }
            if (cv & 0x8000u) {
                // rare flagged outlier: reload this source's grid scalar
                const int sx = sxg + k;
                const float gx = gbase[2 * (n + k)];
                const float gy = gbase[2 * (n + k) + 1];
                const float x0f = floorf(gx);
                const float y0f = floorf(gy);
                const float dx = gx - x0f;
                const float dy = gy - y0f;
                const int x0 = (int)x0f;
                const int y0 = (int)y0f;
                const float wxa[2] = {1.f - dx, dx};
                const float wya[2] = {1.f - dy, dy};
#pragma unroll
                for (int cy2 = 0; cy2 < 2; ++cy2)
#pragma unroll
                    for (int cx2 = 0; cx2 < 2; ++cx2) {
                        const int xi = x0 + cx2, yi = y0 + cy2;
                        if ((unsigned)xi < W && (unsigned)yi < H) {
                            const int ox0 = (xi >> 5) << 5;
                            const int oy0 = (yi >> 5) << 5;
                            const bool covered =
                                (sx >= ox0 - R) && (sx < ox0 + TW + R) &&
                                (sy >= oy0 - R) && (sy < oy0 + TH + R);
                            if (!covered)
                                push_rec(xi, yi, wxa[cx2] * wya[cy2],
                                         v0k[k], v1k[k], v2k[k]);
                        }
                    }
            }
        }
    }
    __syncthreads();

    // ---- Phase B: gather contiguous bin ranges, row-merged, packed fp32 ----
    // Post-placement, binCntP holds INCLUSIVE ends (clamp to NREC; spilled
    // records handled by fix_tiles). start[b] = end[b-1]. Thread owns 4
    // consecutive output rows; bin row by = ry+s feeds cell row by-1
    // (wy=1-dy) and by (wy=dy). Two x-bins of a row form ONE contiguous
    // range [e0,e1) with boundary m: e<m -> wx=dx, e>=m -> wx=1-dx.
    // The 3 ends (bin0-1, bin0, bin0+1) always live in 2 consecutive words.
    // Accumulators are float2 pairs -> v_pk_fma_f32.
    const int cx = tid & 31;
    const int ry = (tid >> 5) * 4;
    float* outb = out + (size_t)b * C * N;
    float* denb = den + (size_t)b * N;

    float2 da0[4];   // (den, a0)
    float2 a12[4];   // (a1, a2)
#pragma unroll
    for (int s = 0; s < 4; ++s) {
        da0[s] = make_float2(0.f, 0.f);
        a12[s] = make_float2(0.f, 0.f);
    }

#pragma unroll
    for (int s = 0; s < 5; ++s) {        // bin row by = ry + s
        const int by = ry + s;
        const int bin0 = by * BDIM + cx;
        const int w = (bin0 == 0) ? 0 : ((bin0 - 1) >> 1);
        const unsigned wa = binCntP[w];
        const unsigned wb = binCntP[w + 1];
        int e0, m, e1;
        if (bin0 == 0) {                 // ends[0], ends[1] in wa
            e0 = 0; m = (int)(wa & 0xffffu); e1 = (int)(wa >> 16);
        } else if (bin0 & 1) {           // bin0-1 even: wa={end[b-1],end[b]}
            e0 = (int)(wa & 0xffffu); m = (int)(wa >> 16);
            e1 = (int)(wb & 0xffffu);
        } else {                         // bin0-1 odd: wa.hi=end[b-1]
            e0 = (int)(wa >> 16); m = (int)(wb & 0xffffu);
            e1 = (int)(wb >> 16);
        }
        e0 = min(e0, NREC); m = min(m, NREC); e1 = min(e1, NREC);
        for (int e = e0; e < e1; ++e) {
            const uint2 rw = rec01[e];
            const float dx = (float)(rw.x & 0xffffu) * (1.f / 65536.f);
            const float dy = (float)(rw.x >> 16) * (1.f / 65536.f);
            const float2 v01 = __half22float2(*(const __half2*)&rw.y);
            const float v2 = __half2float(__ushort_as_half(recV2[e]));
            const float wx = (e < m) ? dx : (1.f - dx);
            const float p = wx * dy;           // row `by` weight
            const float2 ca = make_float2(1.f, v01.x);
            const float2 cb = make_float2(v01.y, v2);
            if (s > 0) {                 // cell row by-1: wy = 1-dy
                const float w2 = wx - p;       // wx*(1-dy)
                const float2 wv = make_float2(w2, w2);
                da0[s - 1] += ca * wv;
                a12[s - 1] += cb * wv;
            }
            if (s < 4) {                 // cell row by: wy = dy
                const float2 wv = make_float2(p, p);
                da0[s] += ca * wv;
                a12[s] += cb * wv;
            }
        }
    }

#pragma unroll
    for (int s = 0; s < 4; ++s) {
        const float d  = da0[s].x;
        const float inv = 1.f / fmaxf(d, EPS);
        const int gi = (ty0 + ry + s) * W + tx0 + cx;
        __builtin_nontemporal_store(d, denb + gi);
        __builtin_nontemporal_store(da0[s].y * inv, outb + gi);
        __builtin_nontemporal_store(a12[s].x * inv, outb + N + gi);
        __builtin_nontemporal_store(a12[s].y * inv, outb + 2 * N + gi);
    }
}

// Apply fixup records exactly: un-normalize affected cells, add, re-normalize.
// One block per tile; records for the same cell are merged (first-index wins).
__global__ __launch_bounds__(64) void fix_tiles(
    float* __restrict__ out,          // [B,C,N] normalized
    float* __restrict__ den,          // [B,N]
    const int* __restrict__ tileCnt,
    const OutlierRec* __restrict__ recs,
    int slots)
{
    const int bid = blockIdx.x;
    int cnt = tileCnt[bid];
    if (cnt <= 0) return;
    cnt = min(cnt, slots);
    const int tid = threadIdx.x;
    if (tid >= cnt) return;

    OutlierRec rec = recs[(size_t)bid * slots + tid];
    float dw = rec.dw, d0 = rec.d0, d1 = rec.d1, d2 = rec.d2;
    bool first = true;
    for (int r2 = 0; r2 < cnt; ++r2) {
        if (r2 == tid) continue;
        OutlierRec o = recs[(size_t)bid * slots + r2];
        if (o.idx == rec.idx) {
            if (r2 < tid) { first = false; break; }
            dw += o.dw; d0 += o.d0; d1 += o.d1; d2 += o.d2;
        }
    }
    if (!first) return;

    const int b = rec.idx >> 20;          // idx / N
    const int cell = rec.idx & (N - 1);
    float* outb = out + (size_t)b * C * N + cell;
    float* dptr = den + ((size_t)b << 20) + cell;

    float d = *dptr;
    const float m = fmaxf(d, EPS);
    float n0 = outb[0] * m;               // recover numerators
    float n1 = outb[N] * m;
    float n2 = outb[2 * N] * m;
    d += dw; n0 += d0; n1 += d1; n2 += d2;
    const float inv = 1.f / fmaxf(d, EPS);
    *dptr = d;
    outb[0]     = n0 * inv;
    outb[N]     = n1 * inv;
    outb[2 * N] = n2 * inv;
}

extern "C" void kernel_launch(void* const* d_in, const int* in_sizes, int n_in,
                              void* d_out, int out_size, void* d_ws, size_t ws_size,
                              hipStream_t stream) {
    const float* im0 = (const float*)d_in[0];   // [B,C,H,W] fp32
    const float* grid = (const float*)d_in[1];  // [B,H,W,2] fp32
    float* out = (float*)d_out;                 // [B,C,H,W] fp32

    // ws layout: [0,16K): per-tile record counts | [16K, 16K+16MB): den |
    //            rest: per-tile fixup record slots
    int* tileCnt = (int*)d_ws;
    float* den = (float*)((char*)d_ws + 16384);
    const size_t rec_off = 16384 + (size_t)B * N * sizeof(float);
    OutlierRec* recs = (OutlierRec*)((char*)d_ws + rec_off);
    int slots = 0;
    if (ws_size > rec_off) {
        size_t avail = (ws_size - rec_off) / sizeof(OutlierRec);
        slots = (int)(avail / NTILES);
        if (slots > 32) slots = 32;
    }

    (void)hipMemsetAsync(tileCnt, 0, NTILES * sizeof(int), stream);

    splat_gather<<<NTILES, 256, 0, stream>>>(im0, grid, out, den,
                                             tileCnt, recs, slots);
    fix_tiles<<<NTILES, 64, 0, stream>>>(out, den, tileCnt, recs, slots);
}

// Round 13
// 143.818 us; speedup vs baseline: 1.0106x; 1.0099x over previous
//
#include <hip/hip_runtime.h>
#include <hip/hip_fp16.h>

// Problem constants (from reference setup_inputs)
#define B 4
#define C 3
#define H 1024
#define W 1024
#define N (H * W)
#define EPS 1e-8f

// Counting-sort bin-and-gather splat: each block owns a 32x32 output tile.
// Sources from the tile+8px window are BIN-SORTED in LDS by integer cell
// (x0,y0) via count -> packed prefix scan -> place (cursor atomics). Each
// output cell gathers its neighboring bins as CONTIGUOUS record ranges,
// accumulating den + 3 channels in fp32 registers (no fp atomics; r2:
// ds_add_f32 bulk scatter is ~1 lane-op/cy).
//
// FINAL (r13): this is the r8 configuration, the session's best measured
// (144.8 us bench, 54 us profile splat). Subsequent experiments and their
// post-mortems, kept for the record:
//  - r9  half2 fractions: FAIL absmax 3.53. Weight precision drives absmax
//    through low-denominator cells (err ~ dv*dw/den, den~1e-3 common at 4M
//    cells). Fractions must stay u16 fixed-point (dw 1.5e-5).
//  - r11 rank-carry (use A1 atomic return, atomic-free A2): REGRESSED
//    54->60.5 us. A no-return ds_add_u32 is cheap; ds_add_rtn_b32 adds a
//    ~120cy dependent wait per source in A1 (9/thread) > the A2 chain saved.
//  - r12 late-pack + packed-fp32 Phase B: VALUBusy 64->55 but time 54->60.
//    Not VALU-issue-bound anymore; the changes traded issue count for
//    dependency depth. Mixed latency regime: no single pipe >60%.
// Remaining structure: splat ~2x its 26us HBM floor; bench total pinned at
// ~145 by ~90us fixed harness overhead (constant across splat 130->54).
//
// Techniques carried (each verified by counters in its round):
//  - counting-sort bins (r5): no ent[] indirection, 2-deep LDS chain,
//    no bin-capacity overflow path.
//  - register-carry A1->A2 (r6): packed fractions cw + status cbp live in
//    regs across the scan; A2 does NO grid reload (FETCH -30MB).
//  - NREC=1536 cap (r6) -> 17 920 B LDS -> 8 blocks/CU; exact spill path.
//  - outlier pre-filter |disp|<=6 (r6): 4-corner check only for ~0.5%.
//  - im0-load skip for empty tasks (r6).
//  - uint2 rec01 (r7): one ds_read_b64 per entry; END-triple via one
//    aligned word-pair read.
//  - nontemporal out/den stores (r7).
#define TW 32
#define TH 32
#define R 8
#define WIN 48                 // TW + 2R
#define NSRC (WIN * WIN)       // 2304 window sources
#define NTASKS (NSRC / 4)      // 576 float4-groups
#define COLG (WIN / 4)         // 12
#define BDIM 33                // bins per axis: x0 in [tx0-1, tx0+31]
#define NBINS (BDIM * BDIM)    // 1089
#define NBINW ((NBINS + 1) / 2)// 545 packed words (2 x u16 each)
#define NREC 1536              // record capacity (cap, exact spill path)
#define NTX (W / TW)           // 32
#define NTY (H / TH)           // 32
#define NTILES (NTX * NTY * B) // 4096

struct OutlierRec { int idx; float dw, d0, d1, d2; };  // idx = b*N + cell

__global__ __launch_bounds__(256, 8) void splat_gather(
    const float* __restrict__ im0,   // [B,C,H,W]
    const float* __restrict__ grid,  // [B,H,W,2]
    float* __restrict__ out,         // [B,C,H,W] NORMALIZED output
    float* __restrict__ den,         // [B,N] denominators (for fixup)
    int* __restrict__ tileCnt,       // [NTILES] record counts (pre-zeroed)
    OutlierRec* __restrict__ recs,   // [NTILES*slots]
    int slots)
{
    __shared__ uint2 rec01[NREC];           // 12288 B (x: dy<<16|dx u16 fx, y: half2(v0,v1))
    __shared__ unsigned short recV2[NREC];  //  3072 B (half(v2) bits)
    __shared__ unsigned binCntP[NBINW];     //  2180 B (2 x u16 per word)
    __shared__ int wtot[4];                 // wave totals for the scan
    // total 17 556 B -> 17 920 alloc -> 8 blocks/CU

    const int bid = blockIdx.x;
    const int b = bid >> 10;             // 1024 tiles per image
    const int t = bid & 1023;
    const int tx0 = (t & (NTX - 1)) * TW;
    const int ty0 = (t >> 5) * TH;
    const int tid = threadIdx.x;

    for (int i = tid; i < NBINW; i += 256) binCntP[i] = 0u;
    __syncthreads();

    const int lx0 = tx0 - R;
    const int ly0 = ty0 - R;

    const float* imb   = im0 + (size_t)b * C * N;
    const float* gbase = grid + (size_t)b * N * 2;

    // helper: push an exact fp32 record to a tile's fixup list
    auto push_rec = [&](int xi, int yi, float w, float v0, float v1, float v2) {
        const int tile = (b << 10) | ((yi >> 5) << 5) | (xi >> 5);
        const int slot = atomicAdd(&tileCnt[tile], 1);
        if (slot < slots) {
            OutlierRec r;
            r.idx = b * N + yi * W + xi;
            r.dw = w; r.d0 = v0 * w; r.d1 = v1 * w; r.d2 = v2 * w;
            recs[(size_t)tile * slots + slot] = r;
        }
    };

    // Per-source register cache carried A1 -> A2 (all indices compile-time).
    unsigned cw[3][4];     // packed fractions dq | eq<<16 (u16 fixed-point)
    unsigned cbp[3][2];    // 2 x u16 per word: (bin+1) | outlier<<15

    // ---- Phase A1: count sources per bin (grid loads only; no-return
    //      atomic -> cheap ds_add_u32) ----
#pragma unroll
    for (int it = 0; it < 3; ++it) {
        cbp[it][0] = 0u; cbp[it][1] = 0u;
        if (it == 2 && tid >= NTASKS - 512) continue;   // only tid<64 has task 3
        const int task = tid + it * 256;
        const int row = task / COLG;                    // 0..47
        const int col = (task - row * COLG) * 4;        // 0,4,...,44
        const int sy = ly0 + row;
        const int sxg = lx0 + col;
        if ((unsigned)sy >= H || (unsigned)sxg >= W) continue;

        const int n = sy * W + sxg;
        const float4 g0 = *(const float4*)(gbase + 2 * n);
        const float4 g1 = *(const float4*)(gbase + 2 * n + 4);
        const float gxk[4] = {g0.x, g0.z, g1.x, g1.z};
        const float gyk[4] = {g0.y, g0.w, g1.y, g1.w};

        unsigned cv[4];
#pragma unroll
        for (int k = 0; k < 4; ++k) {
            const int sx = sxg + k;
            const float gx = gxk[k], gy = gyk[k];
            const float x0f = floorf(gx);
            const float y0f = floorf(gy);
            const float dx = gx - x0f;
            const float dy = gy - y0f;
            const int x0 = (int)x0f;
            const int y0 = (int)y0f;

            {
                unsigned dq = (unsigned)(dx * 65536.0f);
                unsigned eq = (unsigned)(dy * 65536.0f);
                if (dq > 65535u) dq = 65535u;
                if (eq > 65535u) eq = 65535u;
                cw[it][k] = dq | (eq << 16);
            }

            unsigned c = 0u;
            const int bx = x0 - tx0 + 1;
            const int by = y0 - ty0 + 1;
            if ((unsigned)bx < BDIM && (unsigned)by < BDIM) {
                const int bin = by * BDIM + bx;
                atomicAdd(&binCntP[bin >> 1],
                          1u << ((unsigned)(bin & 1) * 16u));
                c = (unsigned)(bin + 1);
            }
            // owner-outlier pre-filter: |disp|<=6 on both axes guarantees all
            // corners covered by their owners' windows.
            if ((unsigned)(sx - tx0) < TW && (unsigned)(sy - ty0) < TH) {
                if (!(fabsf(gx - (float)sx) <= 6.f &&
                      fabsf(gy - (float)sy) <= 6.f)) {
                    bool outl = false;
#pragma unroll
                    for (int cy2 = 0; cy2 < 2; ++cy2)
#pragma unroll
                        for (int cx2 = 0; cx2 < 2; ++cx2) {
                            const int xi = x0 + cx2, yi = y0 + cy2;
                            if ((unsigned)xi < W && (unsigned)yi < H) {
                                const int ox0 = (xi >> 5) << 5;
                                const int oy0 = (yi >> 5) << 5;
                                if (sx < ox0 - R || sx >= ox0 + TW + R ||
                                    sy < oy0 - R || sy >= oy0 + TH + R)
                                    outl = true;
                            }
                        }
                    if (outl) c |= 0x8000u;
                }
            }
            cv[k] = c;
        }
        cbp[it][0] = cv[0] | (cv[1] << 16);
        cbp[it][1] = cv[2] | (cv[3] << 16);
    }
    __syncthreads();

    // ---- Scan: exclusive prefix over 1089 bins, in place, packed u16 ----
    // Thread owns 6 consecutive bins = 3 whole packed words.
    {
        int c[6] = {0, 0, 0, 0, 0, 0};
        const int w0 = tid * 3;
        const bool act = (tid * 6) < NBINS;
        if (act) {
#pragma unroll
            for (int j = 0; j < 3; ++j) {
                const int w = w0 + j;
                const unsigned wv = (w < NBINW) ? binCntP[w] : 0u;
                c[2 * j]     = (int)(wv & 0xffffu);
                c[2 * j + 1] = (int)(wv >> 16);
            }
        }
        const int tsum = c[0] + c[1] + c[2] + c[3] + c[4] + c[5];
        int x = tsum;
#pragma unroll
        for (int off = 1; off < 64; off <<= 1) {
            const int y = __shfl_up(x, off);
            if ((tid & 63) >= off) x += y;
        }
        if ((tid & 63) == 63) wtot[tid >> 6] = x;
        __syncthreads();
        int ex = x - tsum;                         // exclusive within wave
        for (int i = 0; i < (tid >> 6); ++i) ex += wtot[i];
        if (act) {
#pragma unroll
            for (int j = 0; j < 3; ++j) {
                const int w = w0 + j;
                if (w < NBINW) {
                    const unsigned lo = (unsigned)ex; ex += c[2 * j];
                    const unsigned hi = (unsigned)ex; ex += c[2 * j + 1];
                    binCntP[w] = (lo & 0xffffu) | (hi << 16);
                }
            }
        }
    }
    __syncthreads();

    // ---- Phase A2: place records bin-sorted (im0 loads; NO grid reload) ----
#pragma unroll
    for (int it = 0; it < 3; ++it) {
        if (it == 2 && tid >= NTASKS - 512) continue;
        const unsigned p0 = cbp[it][0], p1 = cbp[it][1];
        if (!(p0 | p1)) continue;       // nothing binned, no outliers
        const int task = tid + it * 256;
        const int row = task / COLG;
        const int col = (task - row * COLG) * 4;
        const int sy = ly0 + row;
        const int sxg = lx0 + col;
        const int n = sy * W + sxg;
        const float4 c0 = *(const float4*)(imb + n);
        const float4 c1 = *(const float4*)(imb + N + n);
        const float4 c2 = *(const float4*)(imb + 2 * N + n);
        const float v0k[4] = {c0.x, c0.y, c0.z, c0.w};
        const float v1k[4] = {c1.x, c1.y, c1.z, c1.w};
        const float v2k[4] = {c2.x, c2.y, c2.z, c2.w};

#pragma unroll
        for (int k = 0; k < 4; ++k) {
            const unsigned cv = (((k & 2) ? p1 : p0) >> ((k & 1) * 16)) & 0xffffu;
            const unsigned binp1 = cv & 0x7fffu;
            if (binp1) {
                const int bin = (int)binp1 - 1;
                const unsigned sh = (unsigned)(bin & 1) * 16u;
                const unsigned old = atomicAdd(&binCntP[bin >> 1], 1u << sh);
                const int slot = (int)((old >> sh) & 0xffffu);
                const unsigned w0 = cw[it][k];
                if (slot < NREC) {
                    __half2 h01 = __floats2half2_rn(v0k[k], v1k[k]);
                    uint2 r; r.x = w0; r.y = *(unsigned*)&h01;
                    rec01[slot] = r;
                    recV2[slot] = __half_as_ushort(__float2half_rn(v2k[k]));
                } else {
                    // capacity spill (rare): exact records for corners in MY
                    // tile (neighbor tiles handle theirs).
                    const float dx = (float)(w0 & 0xffffu) * (1.f / 65536.f);
                    const float dy = (float)(w0 >> 16) * (1.f / 65536.f);
                    const int x0 = tx0 - 1 + bin % BDIM;
                    const int y0 = ty0 - 1 + bin / BDIM;
                    const float wxa[2] = {1.f - dx, dx};
                    const float wya[2] = {1.f - dy, dy};
#pragma unroll
                    for (int cy2 = 0; cy2 < 2; ++cy2)
#pragma unroll
                        for (int cx2 = 0; cx2 < 2; ++cx2) {
                            const int xi = x0 + cx2, yi = y0 + cy2;
                            if ((unsigned)(xi - tx0) < TW &&
                                (unsigned)(yi - ty0) < TH)
                                push_rec(xi, yi, wxa[cx2] * wya[cy2],
                                         v0k[k], v1k[k], v2k[k]);
                        }
                }
            }
            if (cv & 0x8000u) {
                // rare flagged outlier: reload this source's grid scalar
                const int sx = sxg + k;
                const float gx = gbase[2 * (n + k)];
                const float gy = gbase[2 * (n + k) + 1];
                const float x0f = floorf(gx);
                const float y0f = floorf(gy);
                const float dx = gx - x0f;
                const float dy = gy - y0f;
                const int x0 = (int)x0f;
                const int y0 = (int)y0f;
                const float wxa[2] = {1.f - dx, dx};
                const float wya[2] = {1.f - dy, dy};
#pragma unroll
                for (int cy2 = 0; cy2 < 2; ++cy2)
#pragma unroll
                    for (int cx2 = 0; cx2 < 2; ++cx2) {
                        const int xi = x0 + cx2, yi = y0 + cy2;
                        if ((unsigned)xi < W && (unsigned)yi < H) {
                            const int ox0 = (xi >> 5) << 5;
                            const int oy0 = (yi >> 5) << 5;
                            const bool covered =
                                (sx >= ox0 - R) && (sx < ox0 + TW + R) &&
                                (sy >= oy0 - R) && (sy < oy0 + TH + R);
                            if (!covered)
                                push_rec(xi, yi, wxa[cx2] * wya[cy2],
                                         v0k[k], v1k[k], v2k[k]);
                        }
                    }
            }
        }
    }
    __syncthreads();

    // ---- Phase B: gather contiguous bin ranges, row-merged ----
    // Post-placement, binCntP holds INCLUSIVE ends (clamp to NREC; spilled
    // records handled by fix_tiles). start[b] = end[b-1]. Thread owns 4
    // consecutive output rows; bin row by = ry+s feeds cell row by-1
    // (wy=1-dy) and by (wy=dy). Two x-bins of a row form ONE contiguous
    // range [e0,e1) with boundary m: e<m -> wx=dx, e>=m -> wx=1-dx.
    // The 3 ends (bin0-1, bin0, bin0+1) always live in 2 consecutive u32
    // words -> one fused word-pair read per bin-row.
    const int cx = tid & 31;
    const int ry = (tid >> 5) * 4;
    float* outb = out + (size_t)b * C * N;
    float* denb = den + (size_t)b * N;

    float d[4]  = {0.f, 0.f, 0.f, 0.f};
    float a0[4] = {0.f, 0.f, 0.f, 0.f};
    float a1[4] = {0.f, 0.f, 0.f, 0.f};
    float a2[4] = {0.f, 0.f, 0.f, 0.f};

#pragma unroll
    for (int s = 0; s < 5; ++s) {        // bin row by = ry + s
        const int by = ry + s;
        const int bin0 = by * BDIM + cx;
        const int w = (bin0 == 0) ? 0 : ((bin0 - 1) >> 1);
        const unsigned wa = binCntP[w];
        const unsigned wb = binCntP[w + 1];
        int e0, m, e1;
        if (bin0 == 0) {                 // ends[0], ends[1] in wa
            e0 = 0; m = (int)(wa & 0xffffu); e1 = (int)(wa >> 16);
        } else if (bin0 & 1) {           // bin0-1 even: wa={end[b-1],end[b]}
            e0 = (int)(wa & 0xffffu); m = (int)(wa >> 16);
            e1 = (int)(wb & 0xffffu);
        } else {                         // bin0-1 odd: wa.hi=end[b-1]
            e0 = (int)(wa >> 16); m = (int)(wb & 0xffffu);
            e1 = (int)(wb >> 16);
        }
        e0 = min(e0, NREC); m = min(m, NREC); e1 = min(e1, NREC);
        for (int e = e0; e < e1; ++e) {
            const uint2 rw = rec01[e];
            const float dx = (float)(rw.x & 0xffffu) * (1.f / 65536.f);
            const float dy = (float)(rw.x >> 16) * (1.f / 65536.f);
            const float2 v01 = __half22float2(*(const __half2*)&rw.y);
            const float v2 = __half2float(__ushort_as_half(recV2[e]));
            const float wx = (e < m) ? dx : (1.f - dx);
            if (s > 0) {                 // cell row by-1: wy = 1-dy
                const float w2 = wx * (1.f - dy);
                d[s - 1] += w2;
                a0[s - 1] += v01.x * w2;
                a1[s - 1] += v01.y * w2;
                a2[s - 1] += v2 * w2;
            }
            if (s < 4) {                 // cell row by: wy = dy
                const float w2 = wx * dy;
                d[s] += w2;
                a0[s] += v01.x * w2;
                a1[s] += v01.y * w2;
                a2[s] += v2 * w2;
            }
        }
    }

#pragma unroll
    for (int s = 0; s < 4; ++s) {
        const float inv = 1.f / fmaxf(d[s], EPS);
        const int gi = (ty0 + ry + s) * W + tx0 + cx;
        __builtin_nontemporal_store(d[s], denb + gi);
        __builtin_nontemporal_store(a0[s] * inv, outb + gi);
        __builtin_nontemporal_store(a1[s] * inv, outb + N + gi);
        __builtin_nontemporal_store(a2[s] * inv, outb + 2 * N + gi);
    }
}

// Apply fixup records exactly: un-normalize affected cells, add, re-normalize.
// One block per tile; records for the same cell are merged (first-index wins).
__global__ __launch_bounds__(64) void fix_tiles(
    float* __restrict__ out,          // [B,C,N] normalized
    float* __restrict__ den,          // [B,N]
    const int* __restrict__ tileCnt,
    const OutlierRec* __restrict__ recs,
    int slots)
{
    const int bid = blockIdx.x;
    int cnt = tileCnt[bid];
    if (cnt <= 0) return;
    cnt = min(cnt, slots);
    const int tid = threadIdx.x;
    if (tid >= cnt) return;

    OutlierRec rec = recs[(size_t)bid * slots + tid];
    float dw = rec.dw, d0 = rec.d0, d1 = rec.d1, d2 = rec.d2;
    bool first = true;
    for (int r2 = 0; r2 < cnt; ++r2) {
        if (r2 == tid) continue;
        OutlierRec o = recs[(size_t)bid * slots + r2];
        if (o.idx == rec.idx) {
            if (r2 < tid) { first = false; break; }
            dw += o.dw; d0 += o.d0; d1 += o.d1; d2 += o.d2;
        }
    }
    if (!first) return;

    const int b = rec.idx >> 20;          // idx / N
    const int cell = rec.idx & (N - 1);
    float* outb = out + (size_t)b * C * N + cell;
    float* dptr = den + ((size_t)b << 20) + cell;

    float d = *dptr;
    const float m = fmaxf(d, EPS);
    float n0 = outb[0] * m;               // recover numerators
    float n1 = outb[N] * m;
    float n2 = outb[2 * N] * m;
    d += dw; n0 += d0; n1 += d1; n2 += d2;
    const float inv = 1.f / fmaxf(d, EPS);
    *dptr = d;
    outb[0]     = n0 * inv;
    outb[N]     = n1 * inv;
    outb[2 * N] = n2 * inv;
}

extern "C" void kernel_launch(void* const* d_in, const int* in_sizes, int n_in,
                              void* d_out, int out_size, void* d_ws, size_t ws_size,
                              hipStream_t stream) {
    const float* im0 = (const float*)d_in[0];   // [B,C,H,W] fp32
    const float* grid = (const float*)d_in[1];  // [B,H,W,2] fp32
    float* out = (float*)d_out;                 // [B,C,H,W] fp32

    // ws layout: [0,16K): per-tile record counts | [16K, 16K+16MB): den |
    //            rest: per-tile fixup record slots
    int* tileCnt = (int*)d_ws;
    float* den = (float*)((char*)d_ws + 16384);
    const size_t rec_off = 16384 + (size_t)B * N * sizeof(float);
    OutlierRec* recs = (OutlierRec*)((char*)d_ws + rec_off);
    int slots = 0;
    if (ws_size > rec_off) {
        size_t avail = (ws_size - rec_off) / sizeof(OutlierRec);
        slots = (int)(avail / NTILES);
        if (slots > 32) slots = 32;
    }

    (void)hipMemsetAsync(tileCnt, 0, NTILES * sizeof(int), stream);

    splat_gather<<<NTILES, 256, 0, stream>>>(im0, grid, out, den,
                                             tileCnt, recs, slots);
    fix_tiles<<<NTILES, 64, 0, stream>>>(out, den, tileCnt, recs, slots);
}